// Round 1
// baseline (243.491 us; speedup 1.0000x reference)
//
#include <hip/hip_runtime.h>

#define BB 2
#define NN 2048
#define HH 16
#define DD 64
#define MODEL 1024

typedef short bf16x8 __attribute__((ext_vector_type(8)));
typedef float f32x4 __attribute__((ext_vector_type(4)));

__device__ __forceinline__ unsigned short f2bf(float x) {
  unsigned int u = __builtin_bit_cast(unsigned int, x);
  u += 0x7fffu + ((u >> 16) & 1u);
  return (unsigned short)(u >> 16);
}

__device__ __forceinline__ f32x4 mfma16(bf16x8 a, bf16x8 b, f32x4 c) {
  return __builtin_amdgcn_mfma_f32_16x16x32_bf16(a, b, c, 0, 0, 0);
}

// dest = lds_base (wave-uniform) + lane*16; 16B per lane
__device__ __forceinline__ void async_copy16(void* lds_base, const void* g) {
  __builtin_amdgcn_global_load_lds(
      (const __attribute__((address_space(1))) void*)g,
      (__attribute__((address_space(3))) void*)lds_base, 16, 0, 0);
}

__global__ void cvt_kernel(const float* __restrict__ src,
                           unsigned short* __restrict__ dst, int n4) {
  int i = blockIdx.x * blockDim.x + threadIdx.x;
  if (i < n4) {
    float4 f = reinterpret_cast<const float4*>(src)[i];
    ushort4 u;
    u.x = f2bf(f.x); u.y = f2bf(f.y); u.z = f2bf(f.z); u.w = f2bf(f.w);
    reinterpret_cast<ushort4*>(dst)[i] = u;
  }
}

// vt[b][h][d][n] = bf16(v[b][n][h*64+d])
__global__ void transpose_v_kernel(const float* __restrict__ v,
                                   unsigned short* __restrict__ vt) {
  __shared__ unsigned short tile[64][65];
  int n0 = blockIdx.x * 64;
  int bh = blockIdx.y;
  int b = bh >> 4, h = bh & 15;
  int c = threadIdx.x & 63;
  int r = threadIdx.x >> 6;
#pragma unroll
  for (int i = 0; i < 16; ++i) {
    int nl = r * 16 + i;
    tile[c][nl] = f2bf(v[((long)(b * NN + n0 + nl)) * MODEL + h * 64 + c]);
  }
  __syncthreads();
#pragma unroll
  for (int i = 0; i < 16; ++i) {
    int d = r * 16 + i;
    vt[((long)(bh * 64 + d)) * NN + n0 + c] = tile[d][c];
  }
}

// biasTab[h][rel+2047], rel in [-2047,2047] — T5 bucketing, bias pre-scale
__global__ void bias_table_kernel(const float* __restrict__ rel_emb,
                                  float* __restrict__ biasTab) {
  int idx = blockIdx.x * 256 + threadIdx.x;
  if (idx >= 4095) return;
  int rel = idx - 2047;
  int nn = rel < 0 ? -rel : rel;
  int bucket;
  if (nn < 8) {
    bucket = nn;
  } else {
    float val = logf((float)nn * 0.125f) / logf(16.0f) * 8.0f;
    int vl = 8 + (int)val;
    if (vl > 15) vl = 15;
    bucket = vl;
  }
  if (rel >= 0) bucket += 16;
#pragma unroll
  for (int h = 0; h < 16; ++h)
    biasTab[h * 4095 + idx] = rel_emb[bucket * 16 + h];
}

// Flash attention: grid (32 qtiles, 32 bh), 256 threads (4 waves x 16 q-rows)
__global__ void flash_kernel(const unsigned short* __restrict__ qb,
                             const unsigned short* __restrict__ kb,
                             const unsigned short* __restrict__ vtb,
                             const float* __restrict__ biasTab,
                             unsigned short* __restrict__ attn) {
  __shared__ __align__(16) unsigned short Kt[64 * 64];      // [n][64], xor-swizzled 16B chunks
  __shared__ __align__(16) unsigned short Vt[64 * 64];      // [d][64n], xor-swizzled
  __shared__ __align__(16) unsigned short Pt[4][16 * 72];   // per-wave, row stride 144B
  __shared__ float biasLds[2112];

  int qt = blockIdx.x, bh = blockIdx.y;
  int b = bh >> 4, h = bh & 15;
  int q0 = qt * 64;
  int tid = threadIdx.x;
  int w = tid >> 6, lane = tid & 63;
  int g = lane >> 4, c = lane & 15;

  // stage needed bias span: rel in [-(q0+63), 2047-q0]
  for (int i = tid; i < 2111; i += 256)
    biasLds[i] = biasTab[h * 4095 + (2047 - (q0 + 63)) + i];

  // Q fragments held in registers for the whole kernel (A-layout: m=lane&15, k=8g+j)
  const unsigned short* qrow =
      qb + ((long)(b * NN + q0 + w * 16 + c)) * MODEL + h * 64;
  bf16x8 qf0 = *reinterpret_cast<const bf16x8*>(qrow + g * 8);
  bf16x8 qf1 = *reinterpret_cast<const bf16x8*>(qrow + 32 + g * 8);

  const unsigned short* kbase = kb + ((long)b * NN) * MODEL + h * 64;
  const unsigned short* vbase = vtb + ((long)bh * 64) * NN;

  f32x4 zero = {0.f, 0.f, 0.f, 0.f};
  f32x4 o[4];
  float m_i[4], l_i[4];
#pragma unroll
  for (int r = 0; r < 4; ++r) { o[r] = zero; m_i[r] = -3.0e38f; l_i[r] = 0.f; }

  int rloc = lane >> 3, p = lane & 7;
  for (int kt = 0; kt < 32; ++kt) {
    __syncthreads();  // prev iter's LDS reads done before restage
#pragma unroll
    for (int t = 0; t < 2; ++t) {
      int row = w * 16 + t * 8 + rloc;        // local tile row, row&7 == rloc
      int lc = p ^ rloc;                       // logical chunk for phys slot p
      async_copy16(&Kt[(w * 16 + t * 8) * 64],
                   kbase + ((long)(kt * 64 + row)) * MODEL + lc * 8);
      async_copy16(&Vt[(w * 16 + t * 8) * 64],
                   vbase + ((long)row) * NN + kt * 64 + lc * 8);
    }
    __syncthreads();  // drains vmcnt: staging complete

    // S = Q K^T  (16 rows x 64 cols per wave)
    f32x4 s[4];
#pragma unroll
    for (int j = 0; j < 4; ++j) {
      int row = j * 16 + c, sw = c & 7;
      bf16x8 k0 = *reinterpret_cast<const bf16x8*>(&Kt[row * 64 + ((0 + g) ^ sw) * 8]);
      bf16x8 k1 = *reinterpret_cast<const bf16x8*>(&Kt[row * 64 + ((4 + g) ^ sw) * 8]);
      s[j] = mfma16(qf0, k0, zero);
      s[j] = mfma16(qf1, k1, s[j]);
    }

    // logits = (S + bias[rel]) * D^-0.5  (scale AFTER bias, as in reference)
    float lg[4][4];
#pragma unroll
    for (int j = 0; j < 4; ++j)
#pragma unroll
      for (int r = 0; r < 4; ++r) {
        int idx = (kt * 64 + j * 16 + c) - (w * 16 + 4 * g + r) + 63;
        lg[j][r] = (s[j][r] + biasLds[idx]) * 0.125f;
      }

    // online softmax, rows live in lanes sharing g (width-16 shuffles)
#pragma unroll
    for (int r = 0; r < 4; ++r) {
      float rmax = fmaxf(fmaxf(lg[0][r], lg[1][r]), fmaxf(lg[2][r], lg[3][r]));
#pragma unroll
      for (int off = 1; off < 16; off <<= 1)
        rmax = fmaxf(rmax, __shfl_xor(rmax, off, 16));
      float mn = fmaxf(m_i[r], rmax);
      float alpha = __expf(m_i[r] - mn);
      m_i[r] = mn;
      float rsum = 0.f;
#pragma unroll
      for (int j = 0; j < 4; ++j) {
        float pe = __expf(lg[j][r] - mn);
        lg[j][r] = pe;
        rsum += pe;
      }
#pragma unroll
      for (int off = 1; off < 16; off <<= 1)
        rsum += __shfl_xor(rsum, off, 16);
      l_i[r] = l_i[r] * alpha + rsum;
#pragma unroll
      for (int jd = 0; jd < 4; ++jd) o[jd][r] *= alpha;
    }

    // P: C-layout -> LDS (padded, conflict-free) -> A-layout frags
#pragma unroll
    for (int j = 0; j < 4; ++j)
#pragma unroll
      for (int r = 0; r < 4; ++r)
        Pt[w][(4 * g + r) * 72 + j * 16 + c] = f2bf(lg[j][r]);

    bf16x8 p0 = *reinterpret_cast<const bf16x8*>(&Pt[w][c * 72 + g * 8]);
    bf16x8 p1 = *reinterpret_cast<const bf16x8*>(&Pt[w][c * 72 + 32 + g * 8]);
#pragma unroll
    for (int jd = 0; jd < 4; ++jd) {
      int row = jd * 16 + c, sw = c & 7;
      bf16x8 v0 = *reinterpret_cast<const bf16x8*>(&Vt[row * 64 + ((0 + g) ^ sw) * 8]);
      bf16x8 v1 = *reinterpret_cast<const bf16x8*>(&Vt[row * 64 + ((4 + g) ^ sw) * 8]);
      o[jd] = mfma16(p0, v0, o[jd]);
      o[jd] = mfma16(p1, v1, o[jd]);
    }
  }

  float inv[4];
#pragma unroll
  for (int r = 0; r < 4; ++r) inv[r] = 1.0f / l_i[r];
#pragma unroll
  for (int jd = 0; jd < 4; ++jd)
#pragma unroll
    for (int r = 0; r < 4; ++r)
      attn[((long)(b * NN + q0 + w * 16 + 4 * g + r)) * MODEL + h * 64 + jd * 16 + c] =
          f2bf(o[jd][r] * inv[r]);
}

// out[i][j] = sum_k attn[i][k] * w[j][k] + b[j]; tile 128(M)x64(N), grid 32x16
__global__ void proj_gemm_kernel(const unsigned short* __restrict__ A,
                                 const unsigned short* __restrict__ Bw,
                                 const float* __restrict__ bias,
                                 float* __restrict__ out) {
  __shared__ __align__(16) unsigned short At[128 * 32];
  __shared__ __align__(16) unsigned short Bt[64 * 32];
  int bm0 = blockIdx.x * 128, bn0 = blockIdx.y * 64;
  int tid = threadIdx.x, w = tid >> 6, lane = tid & 63;
  int g = lane >> 4, c = lane & 15;
  int m0 = (w & 1) * 64, n0 = (w >> 1) * 32;

  f32x4 zero = {0.f, 0.f, 0.f, 0.f};
  f32x4 acc[4][2];
#pragma unroll
  for (int mi = 0; mi < 4; ++mi)
#pragma unroll
    for (int nj = 0; nj < 2; ++nj) acc[mi][nj] = zero;

  int rl4 = lane >> 2, p4 = lane & 3;
  for (int kt = 0; kt < 32; ++kt) {
    __syncthreads();
#pragma unroll
    for (int t = 0; t < 2; ++t) {
      int row = w * 32 + t * 16 + rl4;
      int lc = p4 ^ (rl4 & 3);
      async_copy16(&At[(w * 32 + t * 16) * 32],
                   A + (long)(bm0 + row) * 1024 + kt * 32 + lc * 8);
    }
    {
      int row = w * 16 + rl4;
      int lc = p4 ^ (rl4 & 3);
      async_copy16(&Bt[(w * 16) * 32],
                   Bw + (long)(bn0 + row) * 1024 + kt * 32 + lc * 8);
    }
    __syncthreads();

    bf16x8 af[4], bf[2];
#pragma unroll
    for (int mi = 0; mi < 4; ++mi) {
      int row = m0 + mi * 16 + c;
      af[mi] = *reinterpret_cast<const bf16x8*>(&At[row * 32 + (g ^ (row & 3)) * 8]);
    }
#pragma unroll
    for (int nj = 0; nj < 2; ++nj) {
      int row = n0 + nj * 16 + c;
      bf[nj] = *reinterpret_cast<const bf16x8*>(&Bt[row * 32 + (g ^ (row & 3)) * 8]);
    }
#pragma unroll
    for (int mi = 0; mi < 4; ++mi)
#pragma unroll
      for (int nj = 0; nj < 2; ++nj)
        acc[mi][nj] = mfma16(af[mi], bf[nj], acc[mi][nj]);
  }

#pragma unroll
  for (int mi = 0; mi < 4; ++mi)
#pragma unroll
    for (int nj = 0; nj < 2; ++nj)
#pragma unroll
      for (int r = 0; r < 4; ++r) {
        int row = bm0 + m0 + mi * 16 + 4 * g + r;
        int col = bn0 + n0 + nj * 16 + c;
        out[(long)row * 1024 + col] = acc[mi][nj][r] + bias[col];
      }
}

extern "C" void kernel_launch(void* const* d_in, const int* in_sizes, int n_in,
                              void* d_out, int out_size, void* d_ws, size_t ws_size,
                              hipStream_t stream) {
  const float* q = (const float*)d_in[0];
  const float* k = (const float*)d_in[1];
  const float* v = (const float*)d_in[2];
  const float* rel_emb = (const float*)d_in[3];
  const float* w_out = (const float*)d_in[4];
  const float* b_out = (const float*)d_in[5];
  float* out = (float*)d_out;

  char* ws = (char*)d_ws;
  unsigned short* qb   = (unsigned short*)(ws);
  unsigned short* kb   = (unsigned short*)(ws + (8u << 20));
  unsigned short* vt   = (unsigned short*)(ws + (16u << 20));
  unsigned short* attn = (unsigned short*)(ws + (24u << 20));
  unsigned short* wb   = (unsigned short*)(ws + (32u << 20));
  float* biasTab       = (float*)(ws + (34u << 20));

  hipLaunchKernelGGL(cvt_kernel, dim3(4096), dim3(256), 0, stream,
                     q, qb, BB * NN * MODEL / 4);
  hipLaunchKernelGGL(cvt_kernel, dim3(4096), dim3(256), 0, stream,
                     k, kb, BB * NN * MODEL / 4);
  hipLaunchKernelGGL(cvt_kernel, dim3(1024), dim3(256), 0, stream,
                     w_out, wb, MODEL * MODEL / 4);
  hipLaunchKernelGGL(transpose_v_kernel, dim3(NN / 64, BB * HH), dim3(256), 0, stream,
                     v, vt);
  hipLaunchKernelGGL(bias_table_kernel, dim3(16), dim3(256), 0, stream,
                     rel_emb, biasTab);
  hipLaunchKernelGGL(flash_kernel, dim3(NN / 64, BB * HH), dim3(256), 0, stream,
                     qb, kb, vt, biasTab, attn);
  hipLaunchKernelGGL(proj_gemm_kernel, dim3(32, 16), dim3(256), 0, stream,
                     attn, wb, b_out, out);
}

// Round 2
// 224.555 us; speedup vs baseline: 1.0843x; 1.0843x over previous
//
#include <hip/hip_runtime.h>

#define BB 2
#define NN 2048
#define HH 16
#define MODEL 1024
#define CSC 0.18033688011112042f  // 0.125 * log2(e)

typedef short bf16x8 __attribute__((ext_vector_type(8)));
typedef float f32x4 __attribute__((ext_vector_type(4)));

__device__ __forceinline__ unsigned short f2bf(float x) {
  unsigned int u = __builtin_bit_cast(unsigned int, x);
  u += 0x7fffu + ((u >> 16) & 1u);
  return (unsigned short)(u >> 16);
}

__device__ __forceinline__ unsigned int pack_bf2(float a, float b) {
  unsigned int ua = __builtin_bit_cast(unsigned int, a) + 0x8000u;
  unsigned int ub = __builtin_bit_cast(unsigned int, b) + 0x8000u;
  return __builtin_amdgcn_perm(ub, ua, 0x07060302u);  // lo16=bf(a), hi16=bf(b)
}

__device__ __forceinline__ float fast_exp2(float x) {
#if __has_builtin(__builtin_amdgcn_exp2f)
  return __builtin_amdgcn_exp2f(x);
#else
  return exp2f(x);
#endif
}

__device__ __forceinline__ f32x4 mfma16(bf16x8 a, bf16x8 b, f32x4 c) {
  return __builtin_amdgcn_mfma_f32_16x16x32_bf16(a, b, c, 0, 0, 0);
}

__device__ __forceinline__ void async_copy16(void* lds_base, const void* g) {
  __builtin_amdgcn_global_load_lds(
      (const __attribute__((address_space(1))) void*)g,
      (__attribute__((address_space(3))) void*)lds_base, 16, 0, 0);
}

__global__ void cvt_kernel(const float* __restrict__ src,
                           unsigned short* __restrict__ dst, int n4) {
  int i = blockIdx.x * blockDim.x + threadIdx.x;
  if (i < n4) {
    float4 f = reinterpret_cast<const float4*>(src)[i];
    ushort4 u;
    u.x = f2bf(f.x); u.y = f2bf(f.y); u.z = f2bf(f.z); u.w = f2bf(f.w);
    reinterpret_cast<ushort4*>(dst)[i] = u;
  }
}

// vt[b][h][d][n] = bf16(v[b][n][h*64+d])
__global__ void transpose_v_kernel(const float* __restrict__ v,
                                   unsigned short* __restrict__ vt) {
  __shared__ unsigned short tile[64][65];
  int n0 = blockIdx.x * 64;
  int bh = blockIdx.y;
  int b = bh >> 4, h = bh & 15;
  int c = threadIdx.x & 63;
  int r = threadIdx.x >> 6;
#pragma unroll
  for (int i = 0; i < 16; ++i) {
    int nl = r * 16 + i;
    tile[c][nl] = f2bf(v[((long)(b * NN + n0 + nl)) * MODEL + h * 64 + c]);
  }
  __syncthreads();
#pragma unroll
  for (int i = 0; i < 16; ++i) {
    int d = r * 16 + i;
    vt[((long)(bh * 64 + d)) * NN + n0 + c] = tile[d][c];
  }
}

// biasTab[h][rel+2047] = bias(rel) * 0.125 * log2(e)  (log2-domain, pre-scaled)
__global__ void bias_table_kernel(const float* __restrict__ rel_emb,
                                  float* __restrict__ biasTab) {
  int idx = blockIdx.x * 256 + threadIdx.x;
  if (idx >= 4095) return;
  int rel = idx - 2047;
  int nn = rel < 0 ? -rel : rel;
  int bucket;
  if (nn < 8) {
    bucket = nn;
  } else {
    float val = logf((float)nn * 0.125f) / logf(16.0f) * 8.0f;
    int vl = 8 + (int)val;
    if (vl > 15) vl = 15;
    bucket = vl;
  }
  if (rel >= 0) bucket += 16;
#pragma unroll
  for (int h = 0; h < 16; ++h)
    biasTab[h * 4095 + idx] = rel_emb[bucket * 16 + h] * CSC;
}

// Flash attention v2: waves split key-tiles (kt = w + 4*i), S^T layout,
// K/V direct global->reg, zero in-loop barriers, LDS merge at end.
__global__ __launch_bounds__(256, 2) void flash2(
    const unsigned short* __restrict__ qb, const unsigned short* __restrict__ kb,
    const unsigned short* __restrict__ vtb, const float* __restrict__ biasTab,
    unsigned short* __restrict__ attn) {
  // obuf doubles as per-wave P-buffer in-loop (disjoint phases, barrier between)
  __shared__ __align__(16) float obuf[4 * 64 * 68];  // 69632 B
  __shared__ __align__(16) float scratch[512];       // bias span in-loop / m,l post-loop

  const int qt = blockIdx.x, bh = blockIdx.y;
  const int b = bh >> 4, h = bh & 15;
  const int q0 = qt * 64;
  const int tid = threadIdx.x, w = tid >> 6, lane = tid & 63;
  const int g = lane >> 4, c = lane & 15;

  const float* btab = biasTab + h * 4095 + 2047;
  for (int i = tid; i < 441; i += 256) scratch[i] = btab[i - 220];
  const float cPos = btab[200], cNeg = btab[-200];  // saturated buckets (|rel|>=91)
  __syncthreads();

  // Q B-frags for all 64 q-rows of the block (resident whole kernel)
  bf16x8 qf0[4], qf1[4];
  const unsigned short* qbase = qb + ((long)(b * NN + q0)) * MODEL + h * 64;
#pragma unroll
  for (int nt = 0; nt < 4; ++nt) {
    const unsigned short* r = qbase + (16 * nt + c) * MODEL + 8 * g;
    qf0[nt] = *reinterpret_cast<const bf16x8*>(r);
    qf1[nt] = *reinterpret_cast<const bf16x8*>(r + 32);
  }

  const unsigned short* kbase = kb + ((long)b * NN) * MODEL + h * 64;
  const unsigned short* vbase = vtb + ((long)bh * 64) * NN;

  f32x4 o[4][4];
  float m_i[4], l_i[4];
#pragma unroll
  for (int nt = 0; nt < 4; ++nt) {
    m_i[nt] = -1e30f; l_i[nt] = 0.f;
#pragma unroll
    for (int mt = 0; mt < 4; ++mt) o[mt][nt] = f32x4{0.f, 0.f, 0.f, 0.f};
  }

  unsigned int* Pb = reinterpret_cast<unsigned int*>(obuf);
  const int ProwW = (w * 16 + c) * 36 + 2 * g;  // dword: row stride 36, slot 8mt+2g+t
  const int ProwR = (w * 16 + c) * 36 + 4 * g;  // b128 read base (16B aligned)

  for (int it = 0; it < 8; ++it) {
    const int kt = w + 4 * it;  // this wave's private key-tile
    bf16x8 kf0[4], kf1[4];
    const unsigned short* krow = kbase + (long)(kt * 64) * MODEL;
#pragma unroll
    for (int mt = 0; mt < 4; ++mt) {
      const unsigned short* r = krow + (16 * mt + c) * MODEL + 8 * g;
      kf0[mt] = *reinterpret_cast<const bf16x8*>(r);
      kf1[mt] = *reinterpret_cast<const bf16x8*>(r + 32);
    }
    // S^T = K * Q^T : lane (g,c) reg rr = S[qrow=16nt+c][key=16mt+4g+rr]
    f32x4 s[4][4];
#pragma unroll
    for (int mt = 0; mt < 4; ++mt)
#pragma unroll
      for (int nt = 0; nt < 4; ++nt) {
        s[mt][nt] = mfma16(kf0[mt], qf0[nt], f32x4{0.f, 0.f, 0.f, 0.f});
        s[mt][nt] = mfma16(kf1[mt], qf1[nt], s[mt][nt]);
      }
    // issue V loads now; latency hidden by softmax VALU
    bf16x8 vf0[4], vf1[4];
    const unsigned short* vrow = vbase + kt * 64;
#pragma unroll
    for (int mt = 0; mt < 4; ++mt) {
      const unsigned short* r = vrow + (long)(16 * mt + c) * NN + 8 * g;
      vf0[mt] = *reinterpret_cast<const bf16x8*>(r);
      vf1[mt] = *reinterpret_cast<const bf16x8*>(r + 32);
    }
    // logits (log2-domain): lg = s*CSC + bias2[rel]
    const int lo = kt * 64 - q0 - 63, hi = kt * 64 + 63 - q0;
    if (lo >= 91 || hi <= -91) {  // whole tile in saturated bucket: sgpr constant
      const float cb = (lo >= 91) ? cPos : cNeg;
#pragma unroll
      for (int mt = 0; mt < 4; ++mt)
#pragma unroll
        for (int nt = 0; nt < 4; ++nt)
#pragma unroll
          for (int rr = 0; rr < 4; ++rr)
            s[mt][nt][rr] = s[mt][nt][rr] * CSC + cb;
    } else {
      const int base = kt * 64 + 4 * g - q0 - c + 220;
#pragma unroll
      for (int mt = 0; mt < 4; ++mt)
#pragma unroll
        for (int nt = 0; nt < 4; ++nt) {
          const int idx = base + 16 * mt - 16 * nt;
#pragma unroll
          for (int rr = 0; rr < 4; ++rr)  // rr-consecutive -> ds_read2_b32
            s[mt][nt][rr] = s[mt][nt][rr] * CSC + scratch[idx + rr];
        }
    }
#pragma unroll
    for (int nt = 0; nt < 4; ++nt) {
      // all 64 keys of qrow=16nt+c live in lanes {c,c+16,c+32,c+48}
      float mx = s[0][nt][0];
#pragma unroll
      for (int mt = 0; mt < 4; ++mt)
#pragma unroll
        for (int rr = 0; rr < 4; ++rr) mx = fmaxf(mx, s[mt][nt][rr]);
      mx = fmaxf(mx, __shfl_xor(mx, 16));
      mx = fmaxf(mx, __shfl_xor(mx, 32));
      const float mn = fmaxf(m_i[nt], mx);
      const float al = fast_exp2(m_i[nt] - mn);
      m_i[nt] = mn;
      float sum = 0.f;
      unsigned int pk[4][2];
#pragma unroll
      for (int mt = 0; mt < 4; ++mt)
#pragma unroll
        for (int t = 0; t < 2; ++t) {
          const float p0 = fast_exp2(s[mt][nt][2 * t] - mn);
          const float p1 = fast_exp2(s[mt][nt][2 * t + 1] - mn);
          sum += p0 + p1;
          pk[mt][t] = pack_bf2(p0, p1);  // keys (16mt+4g+2t, +1)
        }
      sum += __shfl_xor(sum, 16);
      sum += __shfl_xor(sum, 32);
      l_i[nt] = l_i[nt] * al + sum;
#pragma unroll
      for (int mt = 0; mt < 4; ++mt) {
        o[mt][nt][0] *= al; o[mt][nt][1] *= al;
        o[mt][nt][2] *= al; o[mt][nt][3] *= al;
      }
      // P: C-layout -> key-sorted dwords in per-wave LDS rows -> B-frags
#pragma unroll
      for (int mt = 0; mt < 4; ++mt)
#pragma unroll
        for (int t = 0; t < 2; ++t)
          Pb[ProwW + 8 * mt + t] = pk[mt][t];
      const bf16x8 pb0 = *reinterpret_cast<const bf16x8*>(&Pb[ProwR]);
      const bf16x8 pb1 = *reinterpret_cast<const bf16x8*>(&Pb[ProwR + 16]);
#pragma unroll
      for (int mt = 0; mt < 4; ++mt) {
        o[mt][nt] = mfma16(vf0[mt], pb0, o[mt][nt]);  // O^T[d][qrow]
        o[mt][nt] = mfma16(vf1[mt], pb1, o[mt][nt]);
      }
    }
  }

  __syncthreads();  // loop done: P region & bias span now dead
  float* ml = scratch;
  if (g == 0) {
#pragma unroll
    for (int nt = 0; nt < 4; ++nt) {
      ml[(w * 64 + 16 * nt + c) * 2] = m_i[nt];
      ml[(w * 64 + 16 * nt + c) * 2 + 1] = l_i[nt];
    }
  }
  float* ob = obuf + w * 64 * 68;  // obuf[w][qrow][68 d-slots]
#pragma unroll
  for (int mt = 0; mt < 4; ++mt)
#pragma unroll
    for (int nt = 0; nt < 4; ++nt)
      *reinterpret_cast<f32x4*>(&ob[(16 * nt + c) * 68 + 16 * mt + 4 * g]) = o[mt][nt];
  __syncthreads();

  // wave w owns output q-rows 16w..16w+15; lane (g,c) -> qrow 16w+c, dims 8g+j & 32+8g+j
  const int qr = 16 * w + c;
  float mu[4], lu[4];
#pragma unroll
  for (int u = 0; u < 4; ++u) {
    mu[u] = ml[(u * 64 + qr) * 2];
    lu[u] = ml[(u * 64 + qr) * 2 + 1];
  }
  float M = fmaxf(fmaxf(mu[0], mu[1]), fmaxf(mu[2], mu[3]));
  float L = 0.f, fu[4];
#pragma unroll
  for (int u = 0; u < 4; ++u) {
    fu[u] = fast_exp2(mu[u] - M);
    L += fu[u] * lu[u];
  }
  const float inv = 1.f / L;
  float acc[16];
#pragma unroll
  for (int j = 0; j < 16; ++j) acc[j] = 0.f;
#pragma unroll
  for (int u = 0; u < 4; ++u) {
    const float* src = obuf + u * 64 * 68 + qr * 68;
    f32x4 r0 = *reinterpret_cast<const f32x4*>(&src[8 * g]);
    f32x4 r1 = *reinterpret_cast<const f32x4*>(&src[8 * g + 4]);
    f32x4 r2 = *reinterpret_cast<const f32x4*>(&src[32 + 8 * g]);
    f32x4 r3 = *reinterpret_cast<const f32x4*>(&src[32 + 8 * g + 4]);
#pragma unroll
    for (int j = 0; j < 4; ++j) {
      acc[j] += fu[u] * r0[j];
      acc[4 + j] += fu[u] * r1[j];
      acc[8 + j] += fu[u] * r2[j];
      acc[12 + j] += fu[u] * r3[j];
    }
  }
  unsigned int od[8];
#pragma unroll
  for (int t = 0; t < 8; ++t) od[t] = pack_bf2(acc[2 * t] * inv, acc[2 * t + 1] * inv);
  unsigned short* orow = attn + ((long)(b * NN + q0 + qr)) * MODEL + h * 64;
  *reinterpret_cast<uint4*>(orow + 8 * g) = uint4{od[0], od[1], od[2], od[3]};
  *reinterpret_cast<uint4*>(orow + 32 + 8 * g) = uint4{od[4], od[5], od[6], od[7]};
}

// out[i][j] = sum_k attn[i][k] * w[j][k] + b[j]; tile 128(M)x64(N), grid 32x16
__global__ void proj_gemm_kernel(const unsigned short* __restrict__ A,
                                 const unsigned short* __restrict__ Bw,
                                 const float* __restrict__ bias,
                                 float* __restrict__ out) {
  __shared__ __align__(16) unsigned short At[128 * 32];
  __shared__ __align__(16) unsigned short Bt[64 * 32];
  int bm0 = blockIdx.x * 128, bn0 = blockIdx.y * 64;
  int tid = threadIdx.x, w = tid >> 6, lane = tid & 63;
  int g = lane >> 4, c = lane & 15;
  int m0 = (w & 1) * 64, n0 = (w >> 1) * 32;

  f32x4 zero = {0.f, 0.f, 0.f, 0.f};
  f32x4 acc[4][2];
#pragma unroll
  for (int mi = 0; mi < 4; ++mi)
#pragma unroll
    for (int nj = 0; nj < 2; ++nj) acc[mi][nj] = zero;

  int rl4 = lane >> 2, p4 = lane & 3;
  for (int kt = 0; kt < 32; ++kt) {
    __syncthreads();
#pragma unroll
    for (int t = 0; t < 2; ++t) {
      int row = w * 32 + t * 16 + rl4;
      int lc = p4 ^ (rl4 & 3);
      async_copy16(&At[(w * 32 + t * 16) * 32],
                   A + (long)(bm0 + row) * 1024 + kt * 32 + lc * 8);
    }
    {
      int row = w * 16 + rl4;
      int lc = p4 ^ (rl4 & 3);
      async_copy16(&Bt[(w * 16) * 32],
                   Bw + (long)(bn0 + row) * 1024 + kt * 32 + lc * 8);
    }
    __syncthreads();

    bf16x8 af[4], bfr[2];
#pragma unroll
    for (int mi = 0; mi < 4; ++mi) {
      int row = m0 + mi * 16 + c;
      af[mi] = *reinterpret_cast<const bf16x8*>(&At[row * 32 + (g ^ (row & 3)) * 8]);
    }
#pragma unroll
    for (int nj = 0; nj < 2; ++nj) {
      int row = n0 + nj * 16 + c;
      bfr[nj] = *reinterpret_cast<const bf16x8*>(&Bt[row * 32 + (g ^ (row & 3)) * 8]);
    }
#pragma unroll
    for (int mi = 0; mi < 4; ++mi)
#pragma unroll
      for (int nj = 0; nj < 2; ++nj)
        acc[mi][nj] = mfma16(af[mi], bfr[nj], acc[mi][nj]);
  }

#pragma unroll
  for (int mi = 0; mi < 4; ++mi)
#pragma unroll
    for (int nj = 0; nj < 2; ++nj)
#pragma unroll
      for (int r = 0; r < 4; ++r) {
        int row = bm0 + m0 + mi * 16 + 4 * g + r;
        int col = bn0 + n0 + nj * 16 + c;
        out[(long)row * 1024 + col] = acc[mi][nj][r] + bias[col];
      }
}

extern "C" void kernel_launch(void* const* d_in, const int* in_sizes, int n_in,
                              void* d_out, int out_size, void* d_ws, size_t ws_size,
                              hipStream_t stream) {
  const float* q = (const float*)d_in[0];
  const float* k = (const float*)d_in[1];
  const float* v = (const float*)d_in[2];
  const float* rel_emb = (const float*)d_in[3];
  const float* w_out = (const float*)d_in[4];
  const float* b_out = (const float*)d_in[5];
  float* out = (float*)d_out;

  char* ws = (char*)d_ws;
  unsigned short* qb   = (unsigned short*)(ws);
  unsigned short* kb   = (unsigned short*)(ws + (8u << 20));
  unsigned short* vt   = (unsigned short*)(ws + (16u << 20));
  unsigned short* attn = (unsigned short*)(ws + (24u << 20));
  unsigned short* wb   = (unsigned short*)(ws + (32u << 20));
  float* biasTab       = (float*)(ws + (34u << 20));

  hipLaunchKernelGGL(cvt_kernel, dim3(4096), dim3(256), 0, stream,
                     q, qb, BB * NN * MODEL / 4);
  hipLaunchKernelGGL(cvt_kernel, dim3(4096), dim3(256), 0, stream,
                     k, kb, BB * NN * MODEL / 4);
  hipLaunchKernelGGL(cvt_kernel, dim3(1024), dim3(256), 0, stream,
                     w_out, wb, MODEL * MODEL / 4);
  hipLaunchKernelGGL(transpose_v_kernel, dim3(NN / 64, BB * HH), dim3(256), 0, stream,
                     v, vt);
  hipLaunchKernelGGL(bias_table_kernel, dim3(16), dim3(256), 0, stream,
                     rel_emb, biasTab);
  hipLaunchKernelGGL(flash2, dim3(NN / 64, BB * HH), dim3(256), 0, stream,
                     qb, kb, vt, biasTab, attn);
  hipLaunchKernelGGL(proj_gemm_kernel, dim3(32, 16), dim3(256), 0, stream,
                     attn, wb, b_out, out);
}